// Round 1
// 983.841 us; speedup vs baseline: 1.1565x; 1.1565x over previous
//
#include <hip/hip_runtime.h>
#include <hip/hip_bf16.h>
#include <math.h>

#define N_ATOMS 200000
#define M_NBR 12
#define F_DIM 64
#define NBR_FEA 41
#define ORIG_F 92
#define B_CRYS 2000
#define APB 100
#define SH_DIM 9
#define NCONV 3
#define HFEA 128
#define EDGES (N_ATOMS * M_NBR)   // 2,400,000

typedef __attribute__((ext_vector_type(8))) short short8;   // 8 bf16 = 4 VGPRs (MFMA A/B frag)
typedef __attribute__((ext_vector_type(4))) float floatx4;  // MFMA C/D frag

// 16B struct with natural float alignment (4B) — row bases are only 4B-aligned
// (stride 41 floats); clang emits unaligned dwordx4 or splits, both correct.
struct f4u { float x, y, z, w; };

__device__ __forceinline__ float softplus_f(float x) {
    return fmaxf(x, 0.0f) + __logf(1.0f + __expf(-fabsf(x)));
}
__device__ __forceinline__ unsigned short f2bf(float f) {
    __hip_bfloat16 h = __float2bfloat16(f);   // RN
    return *reinterpret_cast<unsigned short*>(&h);
}
__device__ __forceinline__ float bf2f(unsigned int u) {
    unsigned int x = u << 16;
    union { unsigned int i; float f; } c; c.i = x; return c.f;
}

// ---------------------------------------------------------------------------
// x = atom_fea @ W_emb + b_emb  (200000x92 @ 92x64), output bf16
// ---------------------------------------------------------------------------
__global__ __launch_bounds__(256) void k_embed(
    const float* __restrict__ atom_fea, const float* __restrict__ W_emb,
    const float* __restrict__ b_emb, unsigned short* __restrict__ x)
{
    __shared__ float ldsW[ORIG_F * F_DIM];   // 23.5 KB
    __shared__ float ldsA[16 * ORIG_F];      // 5.9 KB
    int tid = threadIdx.x;
    for (int i = tid; i < ORIG_F * F_DIM; i += 256) ldsW[i] = W_emb[i];
    long base = (long)blockIdx.x * 16;
    for (int i = tid; i < 16 * ORIG_F; i += 256) ldsA[i] = atom_fea[base * ORIG_F + i];
    __syncthreads();
    int col = tid & 63;
    int rg  = tid >> 6;
    float a0 = 0.f, a1 = 0.f, a2 = 0.f, a3 = 0.f;
    const float* Ar = &ldsA[(rg * 4) * ORIG_F];
    for (int k = 0; k < ORIG_F; ++k) {
        float wv = ldsW[k * F_DIM + col];
        a0 = fmaf(Ar[0 * ORIG_F + k], wv, a0);
        a1 = fmaf(Ar[1 * ORIG_F + k], wv, a1);
        a2 = fmaf(Ar[2 * ORIG_F + k], wv, a2);
        a3 = fmaf(Ar[3 * ORIG_F + k], wv, a3);
    }
    float bb = b_emb[col];
    long o = (base + rg * 4) * F_DIM + col;
    x[o]             = f2bf(a0 + bb);
    x[o + F_DIM]     = f2bf(a1 + bb);
    x[o + 2 * F_DIM] = f2bf(a2 + bb);
    x[o + 3 * F_DIM] = f2bf(a3 + bb);
}

// ---------------------------------------------------------------------------
// k_prep: one-block kernel packing the (tiny, constant) filter weights into
// the exact per-lane MFMA B-fragment layout, so k_filter needs zero staging.
//   wpak[lane*144 + fid*8 + j], fid = (l*3 + nt)*2 + s,
//     value = bf16(Wr1[l][k][n]),  n = nt*16 + (lane&15),
//                                  k = s*32 + (lane>>4)*8 + j, 0-padded.
//   w2p/b1p[l*48 + n]: Wr2[l][n][0] / br1[l][n], 0-padded to 48.
// ---------------------------------------------------------------------------
__global__ __launch_bounds__(256) void k_prep(
    const float* __restrict__ Wr1, const float* __restrict__ br1,
    const float* __restrict__ Wr2, unsigned short* __restrict__ wpak,
    float* __restrict__ w2p, float* __restrict__ b1p)
{
    int t = threadIdx.x;
    for (int i = t; i < 64 * 18 * 8; i += 256) {
        int lane = i / 144;
        int rem  = i - lane * 144;
        int fid  = rem >> 3;
        int j    = rem & 7;
        int l  = fid / 6;
        int rf = fid - l * 6;
        int nt = rf >> 1;
        int s  = rf & 1;
        int n = nt * 16 + (lane & 15);
        int k = s * 32 + (lane >> 4) * 8 + j;
        unsigned short v = 0;
        if (n < NBR_FEA && k < NBR_FEA)
            v = f2bf(Wr1[(l * NBR_FEA + k) * NBR_FEA + n]);
        wpak[i] = v;
    }
    for (int i = t; i < 3 * 48; i += 256) {
        int l = i / 48, n = i - l * 48;
        w2p[i] = (n < NBR_FEA) ? Wr2[(l * NBR_FEA + n) * SH_DIM] : 0.f;
        b1p[i] = (n < NBR_FEA) ? br1[l * NBR_FEA + n] : 0.f;
    }
}

// ---------------------------------------------------------------------------
// Edge filter v2: LDS-free, all 3 layers fused.
//   W0[l][edge] = softplus(e @ Wr1[l] + br1[l]) . Wr2[l][:,0] + br2[l][0]
// A-frags loaded straight from global fp32 (each element read by exactly one
// lane — there is no reuse, so LDS staging was pure overhead). B-frags come
// pre-packed per-lane from k_prep (18 KB, L1-resident). No barriers.
// ---------------------------------------------------------------------------
__global__ __launch_bounds__(256) void k_filter(
    const float* __restrict__ nbr_fea,
    const unsigned short* __restrict__ wpak,
    const float* __restrict__ w2p, const float* __restrict__ b1p,
    const float* __restrict__ br2, float* __restrict__ W0)
{
    int tid  = threadIdx.x;
    int lane = tid & 63;
    int wv   = tid >> 6;
    int sub  = lane & 15;      // m/n index within 16-tile
    int quad = lane >> 4;      // 0..3 -> k-chunk
    long ebase = (long)blockIdx.x * 256;

    // ---- A fragments: 64 rows per wave, cols partitioned over (s,quad) ----
    // s=0: cols quad*8..quad*8+7 (all < 41).  s=1: cols 32+quad*8.. — only
    // quad 0 fully valid, quad 1 has col 40, quads 2,3 are all K-pad (zeros).
    short8 afr[4][2];
    #pragma unroll
    for (int mt = 0; mt < 4; ++mt) {
        long r = ebase + wv * 64 + mt * 16 + sub;
        const float* rowp = nbr_fea + r * NBR_FEA;
        f4u a = *(const f4u*)(rowp + quad * 8);
        f4u b = *(const f4u*)(rowp + quad * 8 + 4);
        short8 f0;
        f0[0] = (short)f2bf(a.x); f0[1] = (short)f2bf(a.y);
        f0[2] = (short)f2bf(a.z); f0[3] = (short)f2bf(a.w);
        f0[4] = (short)f2bf(b.x); f0[5] = (short)f2bf(b.y);
        f0[6] = (short)f2bf(b.z); f0[7] = (short)f2bf(b.w);
        afr[mt][0] = f0;
        short8 f1 = {0, 0, 0, 0, 0, 0, 0, 0};
        if (quad == 0) {
            f4u c = *(const f4u*)(rowp + 32);
            f4u d = *(const f4u*)(rowp + 36);
            f1[0] = (short)f2bf(c.x); f1[1] = (short)f2bf(c.y);
            f1[2] = (short)f2bf(c.z); f1[3] = (short)f2bf(c.w);
            f1[4] = (short)f2bf(d.x); f1[5] = (short)f2bf(d.y);
            f1[6] = (short)f2bf(d.z); f1[7] = (short)f2bf(d.w);
        } else if (quad == 1) {
            f1[0] = (short)f2bf(rowp[40]);   // col 40; 41..47 are K-pad
        }
        afr[mt][1] = f1;
    }

    const unsigned short* bbase = wpak + lane * 144;   // 288 B/lane, 16B-aligned

    #pragma unroll
    for (int l = 0; l < NCONV; ++l) {
        // B fragments for this layer: 6 coalesced 16B loads, L1-resident
        short8 bfr[3][2];
        #pragma unroll
        for (int nt = 0; nt < 3; ++nt)
            #pragma unroll
            for (int s = 0; s < 2; ++s)
                bfr[nt][s] = *(const short8*)(bbase + ((l * 3 + nt) * 2 + s) * 8);

        floatx4 acc[4][3];
        #pragma unroll
        for (int mt = 0; mt < 4; ++mt)
            #pragma unroll
            for (int nt = 0; nt < 3; ++nt)
                acc[mt][nt] = (floatx4){0.f, 0.f, 0.f, 0.f};

        #pragma unroll
        for (int s = 0; s < 2; ++s)
            #pragma unroll
            for (int mt = 0; mt < 4; ++mt)
                #pragma unroll
                for (int nt = 0; nt < 3; ++nt)
                    acc[mt][nt] = __builtin_amdgcn_mfma_f32_16x16x32_bf16(
                        afr[mt][s], bfr[nt][s], acc[mt][nt], 0, 0, 0);

        // epilogue: s = sum_j softplus(H[m][j]+b1[j]) * w2[j] + br2[l][0]
        float w2v[3], b1v[3];
        #pragma unroll
        for (int nt = 0; nt < 3; ++nt) {
            w2v[nt] = w2p[l * 48 + nt * 16 + sub];
            b1v[nt] = b1p[l * 48 + nt * 16 + sub];
        }
        float r2b = br2[l * SH_DIM];
        #pragma unroll
        for (int mt = 0; mt < 4; ++mt) {
            float p[4];
            #pragma unroll
            for (int reg = 0; reg < 4; ++reg) {
                float t = 0.f;
                #pragma unroll
                for (int nt = 0; nt < 3; ++nt)
                    t += softplus_f(acc[mt][nt][reg] + b1v[nt]) * w2v[nt];
                t += __shfl_xor(t, 1);
                t += __shfl_xor(t, 2);
                t += __shfl_xor(t, 4);
                t += __shfl_xor(t, 8);
                p[reg] = t + r2b;
            }
            if (sub == 0) {
                long base = (long)l * EDGES + ebase + wv * 64 + mt * 16 + quad * 4;
                *(floatx4*)&W0[base] = (floatx4){p[0], p[1], p[2], p[3]};
            }
        }
    }
}

// ---------------------------------------------------------------------------
// Conv: g = cscale * sum_j W0_j * x_in[src_j];  x_out = g @ Wtp[l]
// x in bf16. Gather: 4 atoms/wave, lane = (atom<<4)|featquad, dwordx2 loads.
// ---------------------------------------------------------------------------
__global__ __launch_bounds__(256) void k_conv(
    const unsigned short* __restrict__ x_in, const int* __restrict__ nbr_idx,
    const float* __restrict__ W0, const float* __restrict__ Wtp,
    unsigned short* __restrict__ x_out)
{
    __shared__ float g[16][F_DIM];   // 4 KB
    int tid  = threadIdx.x;
    int lane = tid & 63;
    int wv   = tid >> 6;
    int aw   = lane >> 4;            // atom within wave 0..3
    int fq   = lane & 15;            // features 4fq..4fq+3
    const float cscale = 0.28209479177387814f * 0.125f / 12.0f;

    long atom = (long)blockIdx.x * 16 + wv * 4 + aw;
    long eb = atom * M_NBR;
    float4 acc = {0.f, 0.f, 0.f, 0.f};
    #pragma unroll
    for (int j = 0; j < M_NBR; ++j) {
        int   idx = nbr_idx[eb + j];     // broadcast within 16-lane group
        float wj  = W0[eb + j];
        uint2 v = *(const uint2*)(x_in + (size_t)idx * F_DIM + fq * 4);
        acc.x = fmaf(wj, bf2f(v.x & 0xffffu), acc.x);
        acc.y = fmaf(wj, bf2f(v.x >> 16),     acc.y);
        acc.z = fmaf(wj, bf2f(v.y & 0xffffu), acc.z);
        acc.w = fmaf(wj, bf2f(v.y >> 16),     acc.w);
    }
    float4 gv = {acc.x * cscale, acc.y * cscale, acc.z * cscale, acc.w * cscale};
    *(float4*)&g[wv * 4 + aw][fq * 4] = gv;
    __syncthreads();

    // TP: wave wv -> atoms wv*4..+3, lane = output feature
    int f = lane;
    float o0 = 0.f, o1 = 0.f, o2 = 0.f, o3 = 0.f;
    int r0 = wv * 4;
    for (int k4 = 0; k4 < F_DIM; k4 += 4) {
        float4 ga = *(const float4*)&g[r0 + 0][k4];
        float4 gb = *(const float4*)&g[r0 + 1][k4];
        float4 gc = *(const float4*)&g[r0 + 2][k4];
        float4 gd = *(const float4*)&g[r0 + 3][k4];
        #pragma unroll
        for (int t = 0; t < 4; ++t) {
            float wtv = Wtp[(k4 + t) * F_DIM + f];
            float gaa = (t == 0) ? ga.x : (t == 1) ? ga.y : (t == 2) ? ga.z : ga.w;
            float gbb = (t == 0) ? gb.x : (t == 1) ? gb.y : (t == 2) ? gb.z : gb.w;
            float gcc = (t == 0) ? gc.x : (t == 1) ? gc.y : (t == 2) ? gc.z : gc.w;
            float gdd = (t == 0) ? gd.x : (t == 1) ? gd.y : (t == 2) ? gd.z : gd.w;
            o0 = fmaf(gaa, wtv, o0);
            o1 = fmaf(gbb, wtv, o1);
            o2 = fmaf(gcc, wtv, o2);
            o3 = fmaf(gdd, wtv, o3);
        }
    }
    size_t ob = ((size_t)blockIdx.x * 16 + r0) * F_DIM + f;
    x_out[ob]             = f2bf(o0);
    x_out[ob + F_DIM]     = f2bf(o1);
    x_out[ob + 2 * F_DIM] = f2bf(o2);
    x_out[ob + 3 * F_DIM] = f2bf(o3);
}

// ---------------------------------------------------------------------------
// Readout
// ---------------------------------------------------------------------------
__global__ __launch_bounds__(128) void k_readout(
    const unsigned short* __restrict__ x, const int* __restrict__ cidx,
    const float* __restrict__ W_fc, const float* __restrict__ b_fc,
    const float* __restrict__ W_out, const float* __restrict__ b_out,
    float* __restrict__ out, float* __restrict__ hout)
{
    __shared__ float part[2][F_DIM];
    __shared__ float crys[F_DIM];
    __shared__ float hw[HFEA];
    int tid = threadIdx.x;
    int c = blockIdx.x;
    int f = tid & 63, half = tid >> 6;
    const int* ci = cidx + c * APB + half * (APB / 2);
    float p = 0.f;
    for (int a = 0; a < APB / 2; ++a)
        p += bf2f(x[(size_t)ci[a] * F_DIM + f]);
    part[half][f] = p;
    __syncthreads();
    if (tid < F_DIM) crys[tid] = (part[0][tid] + part[1][tid]) * (1.0f / APB);
    __syncthreads();
    float acc = b_fc[tid];
    for (int ff = 0; ff < F_DIM; ++ff)
        acc = fmaf(crys[ff], W_fc[ff * HFEA + tid], acc);
    float h = softplus_f(acc);
    hout[(size_t)c * HFEA + tid] = h;
    hw[tid] = h * W_out[tid];
    __syncthreads();
    if (tid == 0) {
        float s = b_out[0];
        #pragma unroll 16
        for (int j = 0; j < HFEA; ++j) s += hw[j];
        out[c] = s;
    }
}

extern "C" void kernel_launch(void* const* d_in, const int* in_sizes, int n_in,
                              void* d_out, int out_size, void* d_ws, size_t ws_size,
                              hipStream_t stream) {
    const float* atom_fea = (const float*)d_in[0];
    const float* nbr_fea  = (const float*)d_in[1];
    const int*   nbr_idx  = (const int*)d_in[2];
    const int*   cidx     = (const int*)d_in[3];
    // d_in[4] = pos : unused (Y[:, :1] is the constant l=0 channel)
    const float* W_emb = (const float*)d_in[5];
    const float* b_emb = (const float*)d_in[6];
    const float* Wr1   = (const float*)d_in[7];
    const float* br1   = (const float*)d_in[8];
    const float* Wr2   = (const float*)d_in[9];
    const float* br2   = (const float*)d_in[10];
    const float* Wtp   = (const float*)d_in[11];
    const float* W_fc  = (const float*)d_in[12];
    const float* b_fc  = (const float*)d_in[13];
    const float* W_out = (const float*)d_in[14];
    const float* b_out = (const float*)d_in[15];

    float* out  = (float*)d_out;
    float* hout = out + B_CRYS;

    float* W0 = (float*)d_ws;                                   // 3*2.4M fp32
    unsigned short* xA = (unsigned short*)(W0 + 3 * (size_t)EDGES);
    unsigned short* xB = xA + (size_t)N_ATOMS * F_DIM;

    // Packed filter weights live at the START of the xB region: xB is first
    // written by conv#1, which runs after k_filter has consumed wpak.
    // -> zero workspace growth (total stays exactly 80,000,000 B).
    unsigned short* wpak = xB;                    // 64*18*8 = 9216 bf16 (18 KB)
    float* w2p = (float*)(wpak + 64 * 18 * 8);    // 3*48 fp32
    float* b1p = w2p + 3 * 48;                    // 3*48 fp32

    k_prep  <<<1, 256, 0, stream>>>(Wr1, br1, Wr2, wpak, w2p, b1p);
    k_embed <<<N_ATOMS / 16, 256, 0, stream>>>(atom_fea, W_emb, b_emb, xA);
    k_filter<<<EDGES / 256, 256, 0, stream>>>(nbr_fea, wpak, w2p, b1p, br2, W0);
    k_conv  <<<N_ATOMS / 16, 256, 0, stream>>>(xA, nbr_idx, W0,             Wtp,                     xB);
    k_conv  <<<N_ATOMS / 16, 256, 0, stream>>>(xB, nbr_idx, W0 + EDGES,     Wtp + F_DIM * F_DIM,     xA);
    k_conv  <<<N_ATOMS / 16, 256, 0, stream>>>(xA, nbr_idx, W0 + 2 * EDGES, Wtp + 2 * F_DIM * F_DIM, xB);
    k_readout<<<B_CRYS, 128, 0, stream>>>(xB, cidx, W_fc, b_fc, W_out, b_out, out, hout);
}

// Round 2
// 923.583 us; speedup vs baseline: 1.2320x; 1.0652x over previous
//
#include <hip/hip_runtime.h>
#include <hip/hip_bf16.h>
#include <math.h>

#define N_ATOMS 200000
#define M_NBR 12
#define F_DIM 64
#define NBR_FEA 41
#define ORIG_F 92
#define B_CRYS 2000
#define APB 100
#define SH_DIM 9
#define NCONV 3
#define HFEA 128
#define EDGES (N_ATOMS * M_NBR)   // 2,400,000

typedef __attribute__((ext_vector_type(8))) short short8;   // 8 bf16 = 4 VGPRs (MFMA A/B frag)
typedef __attribute__((ext_vector_type(4))) float floatx4;  // MFMA C/D frag

// 16B struct with natural float alignment (4B) — row bases are only 4B-aligned
struct f4u { float x, y, z, w; };

__device__ __forceinline__ unsigned short f2bf(float f) {
    __hip_bfloat16 h = __float2bfloat16(f);   // RN
    return *reinterpret_cast<unsigned short*>(&h);
}
__device__ __forceinline__ float bf2f(unsigned int u) {
    unsigned int x = u << 16;
    union { unsigned int i; float f; } c; c.i = x; return c.f;
}
__device__ __forceinline__ float softplus_f(float x) {
    return fmaxf(x, 0.0f) + __logf(1.0f + __expf(-fabsf(x)));
}

// ---------------------------------------------------------------------------
// x = atom_fea @ W_emb + b_emb  (200000x92 @ 92x64), output bf16
// ---------------------------------------------------------------------------
__global__ __launch_bounds__(256) void k_embed(
    const float* __restrict__ atom_fea, const float* __restrict__ W_emb,
    const float* __restrict__ b_emb, unsigned short* __restrict__ x)
{
    __shared__ float ldsW[ORIG_F * F_DIM];   // 23.5 KB
    __shared__ float ldsA[16 * ORIG_F];      // 5.9 KB
    int tid = threadIdx.x;
    for (int i = tid; i < ORIG_F * F_DIM; i += 256) ldsW[i] = W_emb[i];
    long base = (long)blockIdx.x * 16;
    for (int i = tid; i < 16 * ORIG_F; i += 256) ldsA[i] = atom_fea[base * ORIG_F + i];
    __syncthreads();
    int col = tid & 63;
    int rg  = tid >> 6;
    float a0 = 0.f, a1 = 0.f, a2 = 0.f, a3 = 0.f;
    const float* Ar = &ldsA[(rg * 4) * ORIG_F];
    for (int k = 0; k < ORIG_F; ++k) {
        float wv = ldsW[k * F_DIM + col];
        a0 = fmaf(Ar[0 * ORIG_F + k], wv, a0);
        a1 = fmaf(Ar[1 * ORIG_F + k], wv, a1);
        a2 = fmaf(Ar[2 * ORIG_F + k], wv, a2);
        a3 = fmaf(Ar[3 * ORIG_F + k], wv, a3);
    }
    float bb = b_emb[col];
    long o = (base + rg * 4) * F_DIM + col;
    x[o]             = f2bf(a0 + bb);
    x[o + F_DIM]     = f2bf(a1 + bb);
    x[o + 2 * F_DIM] = f2bf(a2 + bb);
    x[o + 3 * F_DIM] = f2bf(a3 + bb);
}

// ---------------------------------------------------------------------------
// k_prep: pack all constant weights into exact per-lane MFMA fragment layouts.
//  wpak  : Wr1^T as A-frags.  A[i=n][k]: lane holds n = nt*16+(lane&15),
//          k = s*32+(lane>>4)*8+j  ->  wpak[lane*144 + ((l*3+nt)*2+s)*8 + j]
//  b1pk/w2pk : C/D-layout per-lane vectors, n = nt*16+(lane>>4)*4+reg
//          -> [((l*64+lane)*3+nt)*4+reg]
//  wtpak : Wtp as B-frags. B[k][n]: lane holds n = nt*16+(lane&15),
//          k = s*32+(lane>>4)*8+j  ->  [(((l*64+lane)*4+nt)*2+s)*8+j]
// ---------------------------------------------------------------------------
__global__ __launch_bounds__(256) void k_prep(
    const float* __restrict__ Wr1, const float* __restrict__ br1,
    const float* __restrict__ Wr2, const float* __restrict__ Wtp,
    unsigned short* __restrict__ wpak, float* __restrict__ w2pk,
    float* __restrict__ b1pk, unsigned short* __restrict__ wtpak)
{
    int t = threadIdx.x;
    for (int i = t; i < 64 * 18 * 8; i += 256) {
        int lane = i / 144;
        int rem  = i - lane * 144;
        int fid  = rem >> 3;
        int j    = rem & 7;
        int l  = fid / 6;
        int rf = fid - l * 6;
        int nt = rf >> 1;
        int s  = rf & 1;
        int n = nt * 16 + (lane & 15);
        int k = s * 32 + (lane >> 4) * 8 + j;
        unsigned short v = 0;
        if (n < NBR_FEA && k < NBR_FEA)
            v = f2bf(Wr1[(l * NBR_FEA + k) * NBR_FEA + n]);
        wpak[i] = v;
    }
    for (int i = t; i < 3 * 64 * 3 * 4; i += 256) {
        int reg = i & 3;
        int q   = i >> 2;
        int nt  = q % 3;
        int q2  = q / 3;
        int lane = q2 & 63;
        int l    = q2 >> 6;
        int n = nt * 16 + (lane >> 4) * 4 + reg;
        float b = 0.f, w = 0.f;
        if (n < NBR_FEA) {
            b = br1[l * NBR_FEA + n];
            w = Wr2[(l * NBR_FEA + n) * SH_DIM];
        }
        b1pk[i] = b;
        w2pk[i] = w;
    }
    for (int i = t; i < 3 * 64 * 64; i += 256) {
        int j = i & 7;
        int q = i >> 3;
        int s = q & 1;  q >>= 1;
        int nt = q & 3; q >>= 2;
        int lane = q & 63;
        int l    = q >> 6;
        int k = s * 32 + (lane >> 4) * 8 + j;
        int n = nt * 16 + (lane & 15);
        wtpak[i] = f2bf(Wtp[(l * F_DIM + k) * F_DIM + n]);
    }
}

// ---------------------------------------------------------------------------
// Edge filter v3: operand-swapped MFMA  D = W1^T · E^T  (H^T).
// D col = edge (sub), D row = n (quad*4+reg within nt*16 tile) ->
//   the 48-wide n-reduction is 12 in-register terms + 2 shfl_xor (16,32)
//   instead of 16 shfl + 16 adds per mt.  b1 is folded into the MFMA C-init;
//   ln2 folded into w2l so each softplus-dot elem is ~7 inst (2 trans).
// Per-lane E loads are IDENTICAL to v2's A-frags; wpak layout unchanged.
// ---------------------------------------------------------------------------
__global__ __launch_bounds__(256) void k_filter(
    const float* __restrict__ nbr_fea,
    const unsigned short* __restrict__ wpak,
    const float* __restrict__ w2pk, const float* __restrict__ b1pk,
    const float* __restrict__ br2, float* __restrict__ W0)
{
    int tid  = threadIdx.x;
    int lane = tid & 63;
    int wv   = tid >> 6;
    int sub  = lane & 15;      // edge index within 16-tile (D col)
    int quad = lane >> 4;      // k-chunk on load side / n-quad on D side
    long ebase = (long)blockIdx.x * 256;

    // ---- E^T B-fragments: 64 rows per wave, cols partitioned over (s,quad)
    short8 efr[4][2];
    #pragma unroll
    for (int mt = 0; mt < 4; ++mt) {
        long r = ebase + wv * 64 + mt * 16 + sub;
        const float* rowp = nbr_fea + r * NBR_FEA;
        f4u a = *(const f4u*)(rowp + quad * 8);
        f4u b = *(const f4u*)(rowp + quad * 8 + 4);
        short8 f0;
        f0[0] = (short)f2bf(a.x); f0[1] = (short)f2bf(a.y);
        f0[2] = (short)f2bf(a.z); f0[3] = (short)f2bf(a.w);
        f0[4] = (short)f2bf(b.x); f0[5] = (short)f2bf(b.y);
        f0[6] = (short)f2bf(b.z); f0[7] = (short)f2bf(b.w);
        efr[mt][0] = f0;
        short8 f1 = {0, 0, 0, 0, 0, 0, 0, 0};
        if (quad == 0) {
            f4u c = *(const f4u*)(rowp + 32);
            f4u d = *(const f4u*)(rowp + 36);
            f1[0] = (short)f2bf(c.x); f1[1] = (short)f2bf(c.y);
            f1[2] = (short)f2bf(c.z); f1[3] = (short)f2bf(c.w);
            f1[4] = (short)f2bf(d.x); f1[5] = (short)f2bf(d.y);
            f1[6] = (short)f2bf(d.z); f1[7] = (short)f2bf(d.w);
        } else if (quad == 1) {
            f1[0] = (short)f2bf(rowp[40]);   // col 40; 41..47 are K-pad
        }
        efr[mt][1] = f1;
    }

    const unsigned short* abase = wpak + lane * 144;   // 288 B/lane, 16B-aligned

    #pragma unroll
    for (int l = 0; l < NCONV; ++l) {
        short8 wfr[3][2];
        #pragma unroll
        for (int nt = 0; nt < 3; ++nt)
            #pragma unroll
            for (int s = 0; s < 2; ++s)
                wfr[nt][s] = *(const short8*)(abase + ((l * 3 + nt) * 2 + s) * 8);

        floatx4 b1v[3], w2v[3], w2l[3];
        #pragma unroll
        for (int nt = 0; nt < 3; ++nt) {
            b1v[nt] = *(const floatx4*)&b1pk[((l * 64 + lane) * 3 + nt) * 4];
            w2v[nt] = *(const floatx4*)&w2pk[((l * 64 + lane) * 3 + nt) * 4];
            w2l[nt] = w2v[nt] * 0.69314718055994531f;
        }

        floatx4 acc[3][4];
        #pragma unroll
        for (int nt = 0; nt < 3; ++nt)
            #pragma unroll
            for (int mt = 0; mt < 4; ++mt)
                acc[nt][mt] = b1v[nt];          // C-init = b1 (free +b1)

        #pragma unroll
        for (int s = 0; s < 2; ++s)
            #pragma unroll
            for (int nt = 0; nt < 3; ++nt)
                #pragma unroll
                for (int mt = 0; mt < 4; ++mt)
                    acc[nt][mt] = __builtin_amdgcn_mfma_f32_16x16x32_bf16(
                        wfr[nt][s], efr[mt][s], acc[nt][mt], 0, 0, 0);

        float r2b = br2[l * SH_DIM];
        #pragma unroll
        for (int mt = 0; mt < 4; ++mt) {
            float t = 0.f;
            #pragma unroll
            for (int nt = 0; nt < 3; ++nt)
                #pragma unroll
                for (int reg = 0; reg < 4; ++reg) {
                    float x  = acc[nt][mt][reg];
                    float e  = __expf(-fabsf(x));
                    float lg = __log2f(1.0f + e);
                    t = fmaf(fmaxf(x, 0.f), w2v[nt][reg], fmaf(lg, w2l[nt][reg], t));
                }
            t += __shfl_xor(t, 16);
            t += __shfl_xor(t, 32);
            if (quad == 0)
                W0[(long)l * EDGES + ebase + wv * 64 + mt * 16 + sub] = t + r2b;
        }
    }
}

// ---------------------------------------------------------------------------
// Conv v2: gather (8 lanes/atom, 16B loads) -> g bf16 in swizzled LDS ->
// TP via MFMA (g 32x64 @ Wtp 64x64), Wtp pre-packed as per-lane B-frags.
// ---------------------------------------------------------------------------
__global__ __launch_bounds__(256) void k_conv(
    const unsigned short* __restrict__ x_in, const int* __restrict__ nbr_idx,
    const float* __restrict__ W0, const unsigned short* __restrict__ wtp,
    unsigned short* __restrict__ x_out)
{
    __shared__ __align__(16) unsigned short gl[32 * F_DIM];   // 4 KB, XOR-swizzled
    int tid  = threadIdx.x;
    int lane = tid & 63;
    int wv   = tid >> 6;
    int aw   = lane >> 3;            // atom within wave 0..7
    int oct  = lane & 7;             // 16B chunk of the 128B feature row
    const float cscale = 0.28209479177387814f * 0.125f / 12.0f;

    int  al   = wv * 8 + aw;         // atom local 0..31
    long atom = (long)blockIdx.x * 32 + al;
    long eb   = atom * M_NBR;
    float a0=0.f,a1=0.f,a2=0.f,a3=0.f,a4=0.f,a5=0.f,a6=0.f,a7=0.f;
    #pragma unroll
    for (int j = 0; j < M_NBR; ++j) {
        int   idx = nbr_idx[eb + j];
        float wj  = W0[eb + j];
        uint4 v = *(const uint4*)(x_in + (size_t)idx * F_DIM + oct * 8);
        a0 = fmaf(wj, bf2f(v.x & 0xffffu), a0);
        a1 = fmaf(wj, bf2f(v.x >> 16),     a1);
        a2 = fmaf(wj, bf2f(v.y & 0xffffu), a2);
        a3 = fmaf(wj, bf2f(v.y >> 16),     a3);
        a4 = fmaf(wj, bf2f(v.z & 0xffffu), a4);
        a5 = fmaf(wj, bf2f(v.z >> 16),     a5);
        a6 = fmaf(wj, bf2f(v.w & 0xffffu), a6);
        a7 = fmaf(wj, bf2f(v.w >> 16),     a7);
    }
    short8 pk;
    pk[0] = (short)f2bf(a0 * cscale); pk[1] = (short)f2bf(a1 * cscale);
    pk[2] = (short)f2bf(a2 * cscale); pk[3] = (short)f2bf(a3 * cscale);
    pk[4] = (short)f2bf(a4 * cscale); pk[5] = (short)f2bf(a5 * cscale);
    pk[6] = (short)f2bf(a6 * cscale); pk[7] = (short)f2bf(a7 * cscale);
    int wb = (al * 128 + oct * 16) ^ ((al & 7) << 4);
    *(short8*)((char*)gl + wb) = pk;
    __syncthreads();

    // TP: wave -> m-tile (wv&1), n-tiles (wv>>1)*2 + {0,1}
    int sub = lane & 15, quad = lane >> 4;
    int mt = wv & 1;
    int nb = (wv >> 1) * 2;
    short8 afr[2];
    #pragma unroll
    for (int s = 0; s < 2; ++s) {
        int row = mt * 16 + sub;
        int rb = (row * 128 + s * 64 + quad * 16) ^ ((row & 7) << 4);
        afr[s] = *(const short8*)((const char*)gl + rb);
    }
    const unsigned short* bb = wtp + lane * 64;   // 128 B/lane B-frags
    floatx4 acc[2] = {{0.f,0.f,0.f,0.f},{0.f,0.f,0.f,0.f}};
    #pragma unroll
    for (int s = 0; s < 2; ++s)
        #pragma unroll
        for (int nti = 0; nti < 2; ++nti) {
            short8 bfr = *(const short8*)(bb + (nb + nti) * 16 + s * 8);
            acc[nti] = __builtin_amdgcn_mfma_f32_16x16x32_bf16(afr[s], bfr, acc[nti], 0, 0, 0);
        }
    size_t ob = ((size_t)blockIdx.x * 32 + mt * 16 + quad * 4) * F_DIM + nb * 16 + sub;
    #pragma unroll
    for (int nti = 0; nti < 2; ++nti)
        #pragma unroll
        for (int reg = 0; reg < 4; ++reg)
            x_out[ob + (size_t)reg * F_DIM + nti * 16] = f2bf(acc[nti][reg]);
}

// ---------------------------------------------------------------------------
// Readout
// ---------------------------------------------------------------------------
__global__ __launch_bounds__(128) void k_readout(
    const unsigned short* __restrict__ x, const int* __restrict__ cidx,
    const float* __restrict__ W_fc, const float* __restrict__ b_fc,
    const float* __restrict__ W_out, const float* __restrict__ b_out,
    float* __restrict__ out, float* __restrict__ hout)
{
    __shared__ float part[2][F_DIM];
    __shared__ float crys[F_DIM];
    __shared__ float hw[HFEA];
    int tid = threadIdx.x;
    int c = blockIdx.x;
    int f = tid & 63, half = tid >> 6;
    const int* ci = cidx + c * APB + half * (APB / 2);
    float p = 0.f;
    for (int a = 0; a < APB / 2; ++a)
        p += bf2f(x[(size_t)ci[a] * F_DIM + f]);
    part[half][f] = p;
    __syncthreads();
    if (tid < F_DIM) crys[tid] = (part[0][tid] + part[1][tid]) * (1.0f / APB);
    __syncthreads();
    float acc = b_fc[tid];
    for (int ff = 0; ff < F_DIM; ++ff)
        acc = fmaf(crys[ff], W_fc[ff * HFEA + tid], acc);
    float h = softplus_f(acc);
    hout[(size_t)c * HFEA + tid] = h;
    hw[tid] = h * W_out[tid];
    __syncthreads();
    if (tid == 0) {
        float s = b_out[0];
        #pragma unroll 16
        for (int j = 0; j < HFEA; ++j) s += hw[j];
        out[c] = s;
    }
}

extern "C" void kernel_launch(void* const* d_in, const int* in_sizes, int n_in,
                              void* d_out, int out_size, void* d_ws, size_t ws_size,
                              hipStream_t stream) {
    const float* atom_fea = (const float*)d_in[0];
    const float* nbr_fea  = (const float*)d_in[1];
    const int*   nbr_idx  = (const int*)d_in[2];
    const int*   cidx     = (const int*)d_in[3];
    // d_in[4] = pos : unused (Y[:, :1] is the constant l=0 channel)
    const float* W_emb = (const float*)d_in[5];
    const float* b_emb = (const float*)d_in[6];
    const float* Wr1   = (const float*)d_in[7];
    const float* br1   = (const float*)d_in[8];
    const float* Wr2   = (const float*)d_in[9];
    const float* br2   = (const float*)d_in[10];
    const float* Wtp   = (const float*)d_in[11];
    const float* W_fc  = (const float*)d_in[12];
    const float* b_fc  = (const float*)d_in[13];
    const float* W_out = (const float*)d_in[14];
    const float* b_out = (const float*)d_in[15];

    float* out  = (float*)d_out;
    float* hout = out + B_CRYS;

    float* W0 = (float*)d_ws;                                   // 3*2.4M fp32
    unsigned short* xA = (unsigned short*)(W0 + 3 * (size_t)EDGES);
    unsigned short* xB = xA + (size_t)N_ATOMS * F_DIM;

    // Filter-only packs alias the START of xB (consumed before conv#1 writes xB).
    unsigned short* wpak = xB;                    // 9216 bf16 (18 KB)
    float* w2pk = (float*)(wpak + 9216);          // 2304 fp32
    float* b1pk = w2pk + 2304;                    // 2304 fp32
    // Wtp B-frag pack must survive through conv#3 -> park it in the hout
    // scratch region of d_out (k_readout fully overwrites hout afterwards).
    unsigned short* wtpak = (unsigned short*)(hout + 128000);   // 12288 bf16 (24.6 KB)

    k_prep  <<<1, 256, 0, stream>>>(Wr1, br1, Wr2, Wtp, wpak, w2pk, b1pk, wtpak);
    k_embed <<<N_ATOMS / 16, 256, 0, stream>>>(atom_fea, W_emb, b_emb, xA);
    k_filter<<<EDGES / 256, 256, 0, stream>>>(nbr_fea, wpak, w2pk, b1pk, br2, W0);
    k_conv  <<<N_ATOMS / 32, 256, 0, stream>>>(xA, nbr_idx, W0,             wtpak,            xB);
    k_conv  <<<N_ATOMS / 32, 256, 0, stream>>>(xB, nbr_idx, W0 + EDGES,     wtpak + 4096,     xA);
    k_conv  <<<N_ATOMS / 32, 256, 0, stream>>>(xA, nbr_idx, W0 + 2 * EDGES, wtpak + 2 * 4096, xB);
    k_readout<<<B_CRYS, 128, 0, stream>>>(xB, cidx, W_fc, b_fc, W_out, b_out, out, hout);
}